// Round 8
// baseline (4837.144 us; speedup 1.0000x reference)
//
#include <hip/hip_runtime.h>

#define SEQ 512
#define BB 64
#define IN_DIM 128
#define HH 256
#define NL 6
#define G3 768
#define SA 520          // LDS stride (bf16) for activation rows
#define GPL 4           // batch-groups per layer
#define MB 16           // batches per group (MFMA M)
#define CHUNK 8         // steps per sync
#define NSLOT 4         // ring chunks

typedef short short8 __attribute__((ext_vector_type(8)));
typedef short short4v __attribute__((ext_vector_type(4)));
typedef float f32x4 __attribute__((ext_vector_type(4)));

#define L0_FRAGS (48*12)                 // layer0: KT=12
#define LN_FRAGS (48*16)                 // layers1-5: KT=16
#define TOT_FRAGS (L0_FRAGS + 5*LN_FRAGS)            // 4416
#define STREAM_SHORTS ((size_t)TOT_FRAGS*512)        // frag = 64 lanes x 8 shorts
#define FR_SLOT_SH ((size_t)CHUNK*MB*HH)             // 32768 shorts / chunk-slot
#define FR_TOTAL_SH ((size_t)5*GPL*NSLOT*FR_SLOT_SH)
#define FLAGS_OFF_B ((STREAM_SHORTS + FR_TOTAL_SH)*2)
#define NFLAG_INTS (16 + 2*NL*GPL*16)

__device__ __forceinline__ short f2bf(float f) {
    unsigned u = __builtin_bit_cast(unsigned, f);
    u += 0x7fffu + ((u >> 16) & 1u);   // RNE
    return (short)(u >> 16);
}
__device__ __forceinline__ float sigm(float v) { return __fdividef(1.f, 1.f + __expf(-v)); }
__device__ __forceinline__ float tanh_f(float v) { float e = __expf(2.f * v); return 1.f - __fdividef(2.f, e + 1.f); }

__device__ __forceinline__ void spin1(int* p, int target, unsigned long long ddl) {
    if (__hip_atomic_load(p, __ATOMIC_RELAXED, __HIP_MEMORY_SCOPE_AGENT) >= target) return;
    for (;;) {
        __builtin_amdgcn_s_sleep(2);
        if (__hip_atomic_load(p, __ATOMIC_RELAXED, __HIP_MEMORY_SCOPE_AGENT) >= target) return;
        if (__builtin_amdgcn_s_memrealtime() > ddl) return;   // fail-visible
    }
}

// ---- prep: fp32 weights -> bf16 MFMA B-fragment stream ----
// frag id layout: layer base + kt*48 + nt, nt = jt*3 + gate (wave w owns nt 6w..6w+5)
__global__ __launch_bounds__(256) void prep_frags(
    const float* __restrict__ w_ih0, const float* __restrict__ w_ih_rest,
    const float* __restrict__ w_hh, short* __restrict__ stream)
{
    int id = blockIdx.x * 256 + threadIdx.x;
    if (id >= TOT_FRAGS * 64) return;
    int fid = id >> 6, lane = id & 63;
    int l, rem, KIN;
    if (fid < L0_FRAGS) { l = 0; rem = fid; KIN = IN_DIM; }
    else { int z = fid - L0_FRAGS; l = 1 + z / LN_FRAGS; rem = z - (l - 1) * LN_FRAGS; KIN = HH; }
    int kt = rem / 48, nt = rem % 48;
    int jt = nt / 3, gate = nt - jt * 3;
    int jj = lane & 15, q2 = lane >> 4;
    int row = gate * HH + jt * 16 + jj;
    int k0 = kt * 32 + q2 * 8;
    const float* src;
    if (k0 < KIN) {
        src = (l == 0) ? (w_ih0 + (size_t)row * IN_DIM + k0)
                       : (w_ih_rest + (size_t)(l - 1) * G3 * HH + (size_t)row * HH + k0);
    } else {
        src = w_hh + (size_t)l * G3 * HH + (size_t)row * HH + (k0 - KIN);
    }
    float4 a = *(const float4*)src;
    float4 c = *(const float4*)(src + 4);
    short8 v;
    v[0] = f2bf(a.x); v[1] = f2bf(a.y); v[2] = f2bf(a.z); v[3] = f2bf(a.w);
    v[4] = f2bf(c.x); v[5] = f2bf(c.y); v[6] = f2bf(c.z); v[7] = f2bf(c.w);
    *((short8*)stream + (size_t)fid * 64 + lane) = v;
}

template<int KTL, int KS>
__device__ __forceinline__ void compute_step(const short* sAm, const short8* bs,
                                             int wave, int lane, f32x4* acc)
{
    const int arow = (lane & 15) * SA + ((lane >> 4) * 8);
    const int w6 = wave * 6;
    #pragma unroll
    for (int kt = 0; kt < KTL; ++kt) {
        short8 a = *reinterpret_cast<const short8*>(&sAm[arow + kt * 32]);
        const short8* bp = bs + ((size_t)(kt * 48 + w6) * 64 + lane);
        short8 b0 = bp[0 * 64], b1 = bp[1 * 64], b2 = bp[2 * 64];
        short8 b3 = bp[3 * 64], b4 = bp[4 * 64], b5 = bp[5 * 64];
        acc[0] = __builtin_amdgcn_mfma_f32_16x16x32_bf16(a, b0, acc[0], 0, 0, 0);
        acc[1] = __builtin_amdgcn_mfma_f32_16x16x32_bf16(a, b1, acc[1], 0, 0, 0);
        if (kt < KS) acc[2] = __builtin_amdgcn_mfma_f32_16x16x32_bf16(a, b2, acc[2], 0, 0, 0);
        else         acc[3] = __builtin_amdgcn_mfma_f32_16x16x32_bf16(a, b2, acc[3], 0, 0, 0);
        acc[4] = __builtin_amdgcn_mfma_f32_16x16x32_bf16(a, b3, acc[4], 0, 0, 0);
        acc[5] = __builtin_amdgcn_mfma_f32_16x16x32_bf16(a, b4, acc[5], 0, 0, 0);
        if (kt < KS) acc[6] = __builtin_amdgcn_mfma_f32_16x16x32_bf16(a, b5, acc[6], 0, 0, 0);
        else         acc[7] = __builtin_amdgcn_mfma_f32_16x16x32_bf16(a, b5, acc[7], 0, 0, 0);
    }
}

__global__ __launch_bounds__(512, 1) void gru_persist(
    const float* __restrict__ x, const float* __restrict__ h0,
    const float* __restrict__ b_ih, const float* __restrict__ b_hh,
    float* __restrict__ y, const short* __restrict__ stream,
    short* __restrict__ fring, int* __restrict__ flags)
{
    extern __shared__ short sAm[];   // dyn 65536B: [16][SA] activations + pad (forces 1 WG/CU)
    const int tid = threadIdx.x;
    const unsigned long long ddl = __builtin_amdgcn_s_memrealtime() + 1000000000ull;

    const int xcc = __builtin_amdgcn_s_getreg(20 | (31 << 11)) & 0xf;  // HW_REG_XCC_ID
    if (xcc >= NL) return;
    __shared__ int s_slot;
    if (tid == 0) s_slot = __hip_atomic_fetch_add(&flags[xcc], 1, __ATOMIC_RELAXED, __HIP_MEMORY_SCOPE_AGENT);
    __syncthreads();
    const int g = s_slot;
    if (g >= GPL) return;

    const int l = xcc;
    const int lane = tid & 63;
    const int wave = tid >> 6;
    const int q = lane >> 4;
    const int jj = lane & 15;
    const int KINC = (l == 0) ? IN_DIM : HH;

    int* seqf  = flags + 16 + (l * GPL + g) * 16;                    // own publish (l<5)
    int* cseqf = flags + 16 + NL * GPL * 16 + (l * GPL + g) * 16;    // own consume-progress (l>0)
    int* seq_prev  = flags + 16 + ((l - 1) * GPL + g) * 16;
    int* cseq_next = flags + 16 + NL * GPL * 16 + ((l + 1) * GPL + g) * 16;

    const short8* bs = (const short8*)stream + (size_t)((l == 0) ? 0 : (L0_FRAGS + (l - 1) * LN_FRAGS)) * 64;

    // ---- per-lane state: h carried in registers (fp32), bf16 copy in LDS ----
    // lane owns (b = 4q+r, j = (2*wave+jt2)*16 + jj) for jt2 in {0,1}, r in {0..3}
    float hcur[8];
    float bR[2], bZ[2], bNx[2], bNh[2];
    #pragma unroll
    for (int jt2 = 0; jt2 < 2; ++jt2) {
        int j = (2 * wave + jt2) * 16 + jj;
        bR[jt2]  = b_ih[l * G3 + j] + b_hh[l * G3 + j];
        bZ[jt2]  = b_ih[l * G3 + HH + j] + b_hh[l * G3 + HH + j];
        bNx[jt2] = b_ih[l * G3 + 2 * HH + j];
        bNh[jt2] = b_hh[l * G3 + 2 * HH + j];
        #pragma unroll
        for (int r = 0; r < 4; ++r) {
            int b = 4 * q + r;
            float v = h0[((size_t)l * BB + g * MB + b) * HH + j];
            hcur[jt2 * 4 + r] = v;
        }
    }
    // bf16 h(-1) into LDS h-region
    for (int i = tid; i < MB * HH; i += 512) {
        int b = i >> 8, j = i & 255;
        sAm[b * SA + KINC + j] = f2bf(h0[((size_t)l * BB + g * MB + b) * HH + j]);
    }

    for (int t = 0; t < SEQ; ++t) {
        // ---- chunk-boundary sync (once per 8 steps) ----
        if ((t & 7) == 0) {
            if (tid == 0) {
                if (l > 0) spin1(seq_prev, t + CHUNK, ddl);
                if (l < NL - 1 && t >= NSLOT * CHUNK) spin1(cseq_next, t - (NSLOT - 1) * CHUNK, ddl);
            }
            if (wave == 0) __builtin_amdgcn_fence(__ATOMIC_ACQUIRE, "agent");
            __syncthreads();
        }

        const int slot = (t >> 3) & (NSLOT - 1);

        // ---- stage x-part into LDS cols [0,KINC) ----
        if (l == 0) {
            const float* xt = x + ((size_t)t * BB + g * MB) * IN_DIM;
            int row = tid >> 5, col = (tid & 31) * 4;
            float4 vv = *(const float4*)(xt + row * IN_DIM + col);
            short4v s;
            s[0] = f2bf(vv.x); s[1] = f2bf(vv.y); s[2] = f2bf(vv.z); s[3] = f2bf(vv.w);
            *reinterpret_cast<short4v*>(&sAm[row * SA + col]) = s;
        } else {
            const short* frsrc = fring + (((size_t)((l - 1) * GPL + g) * NSLOT + slot)) * FR_SLOT_SH
                               + (size_t)(t & 7) * MB * HH;
            int row = tid >> 5, col = (tid & 31) * 8;
            short8 v = *(const short8*)&frsrc[row * HH + col];
            *reinterpret_cast<short8*>(&sAm[row * SA + col]) = v;
        }
        __syncthreads();   // x staged + h(t-1) writes (prev epilogue) visible

        // ---- MFMA: all 768 gate-rows for 16 batches ----
        f32x4 acc[8] = {};
        if (l == 0) compute_step<12, 4>(sAm, bs, wave, lane, acc);
        else        compute_step<16, 8>(sAm, bs, wave, lane, acc);
        __syncthreads();   // all A-reads done before h-region overwrite

        // ---- gates + h update (registers) + stores ----
        short* frdst = fring + (((size_t)(l * GPL + g) * NSLOT + slot)) * FR_SLOT_SH
                     + (size_t)(t & 7) * MB * HH;
        float* ydst = y + (size_t)t * BB * HH + (size_t)g * MB * HH;
        #pragma unroll
        for (int jt2 = 0; jt2 < 2; ++jt2) {
            int j = (2 * wave + jt2) * 16 + jj;
            #pragma unroll
            for (int r = 0; r < 4; ++r) {
                int b = 4 * q + r;
                float ho = hcur[jt2 * 4 + r];
                float rg = sigm(acc[jt2 * 4 + 0][r] + bR[jt2]);
                float zg = sigm(acc[jt2 * 4 + 1][r] + bZ[jt2]);
                float ng = tanh_f(acc[jt2 * 4 + 2][r] + bNx[jt2] + rg * (acc[jt2 * 4 + 3][r] + bNh[jt2]));
                float hn = ng + zg * (ho - ng);
                hcur[jt2 * 4 + r] = hn;
                short hb = f2bf(hn);
                sAm[b * SA + KINC + j] = hb;       // h for next step's A
                if (l < NL - 1) frdst[b * HH + j] = hb;
                else            ydst[b * HH + j] = hn;
            }
        }
        __syncthreads();   // drains all waves' global stores before publish

        if ((t & 7) == 7 && tid == 0) {
            if (l < NL - 1)
                __hip_atomic_store(seqf, t + 1, __ATOMIC_RELEASE, __HIP_MEMORY_SCOPE_AGENT);
            if (l > 0)
                __hip_atomic_store(cseqf, t + 1, __ATOMIC_RELEASE, __HIP_MEMORY_SCOPE_AGENT);
        }
    }

    // ---- final hidden state from registers ----
    #pragma unroll
    for (int jt2 = 0; jt2 < 2; ++jt2) {
        int j = (2 * wave + jt2) * 16 + jj;
        #pragma unroll
        for (int r = 0; r < 4; ++r) {
            int b = 4 * q + r;
            y[(size_t)SEQ * BB * HH + (size_t)l * BB * HH + (size_t)(g * MB + b) * HH + j] = hcur[jt2 * 4 + r];
        }
    }
}

extern "C" void kernel_launch(void* const* d_in, const int* in_sizes, int n_in,
                              void* d_out, int out_size, void* d_ws, size_t ws_size,
                              hipStream_t stream) {
    (void)in_sizes; (void)n_in; (void)out_size; (void)ws_size;
    const float* x         = (const float*)d_in[0];
    const float* h0        = (const float*)d_in[1];
    const float* w_ih0     = (const float*)d_in[2];
    const float* w_ih_rest = (const float*)d_in[3];
    const float* w_hh      = (const float*)d_in[4];
    const float* b_ih      = (const float*)d_in[5];
    const float* b_hh      = (const float*)d_in[6];
    float* y = (float*)d_out;

    short* wstream = (short*)d_ws;
    short* fring   = wstream + STREAM_SHORTS;
    int*   flags   = (int*)((char*)d_ws + FLAGS_OFF_B);

    (void)hipMemsetAsync(flags, 0, NFLAG_INTS * sizeof(int), stream);
    prep_frags<<<(TOT_FRAGS * 64) / 256, 256, 0, stream>>>(w_ih0, w_ih_rest, w_hh, wstream);
    // dyn LDS 64KB (sAm 16*520*2 = 16.6KB used; rest pads past 80KB -> 1 WG/CU)
    gru_persist<<<256, 512, 65536, stream>>>(x, h0, b_ih, b_hh, y, wstream, fring, flags);
}